// Round 6
// baseline (4570.685 us; speedup 1.0000x reference)
//
#include <hip/hip_runtime.h>
#include <hip/hip_bf16.h>
#include <cstdint>
#include <cstddef>

#define LOG2E 1.44269504088896340736f

using f32x4 = __attribute__((ext_vector_type(4))) float;
using s16x8 = __attribute__((ext_vector_type(8))) short;

static __device__ __forceinline__ float bf2f(unsigned short u) {
  union { unsigned int i; float f; } v; v.i = ((unsigned int)u) << 16; return v.f;
}
static __device__ __forceinline__ unsigned short f2bf(float f) {
  union { float f; unsigned int i; } v; v.f = f;
  unsigned int r = v.i + 0x7fffu + ((v.i >> 16) & 1u);
  return (unsigned short)(r >> 16);
}
static __device__ __forceinline__ float wredmax(float v) {
  #pragma unroll
  for (int m = 32; m > 0; m >>= 1) v = fmaxf(v, __shfl_xor(v, m, 64));
  return v;
}
static __device__ __forceinline__ float wredsum(float v) {
  #pragma unroll
  for (int m = 32; m > 0; m >>= 1) v += __shfl_xor(v, m, 64);
  return v;
}

// ---------------------------------------------------------------------------
// Transform kernel (unchanged).
// ---------------------------------------------------------------------------
__global__ void ktrans(const float* __restrict__ W1, const float* __restrict__ b1,
                       const float* __restrict__ Wih_in, const float* __restrict__ bih,
                       const float* __restrict__ Whh, const float* __restrict__ bhh,
                       const float* __restrict__ Wfc, const float* __restrict__ bfc,
                       const float* __restrict__ yhist,
                       unsigned short* __restrict__ WB1, unsigned short* __restrict__ WBhh,
                       unsigned short* __restrict__ WB1e, float* __restrict__ b1s,
                       float* __restrict__ Wihs, float* __restrict__ gbias,
                       float* __restrict__ yh2)
{
  int idx = blockIdx.x * 256 + threadIdx.x;
  const float TS = 2.f * LOG2E;
  if (idx < 131072) {                       // WB1: (k,e')
    int k = idx >> 8, e = idx & 255;
    WB1[((k >> 3) * 256 + e) * 8 + (k & 7)] = f2bf(TS * W1[e * 768 + k]);
    return;
  }
  idx -= 131072;
  if (idx < 262144) {                       // WBhh: (k,j)
    int k = idx >> 10, j = idx & 1023;
    float sc = ((j >> 8) == 2) ? TS : -LOG2E;
    WBhh[((k >> 3) * 1024 + j) * 8 + (k & 7)] = f2bf(sc * Whh[j * 256 + k]);
    return;
  }
  idx -= 262144;
  if (idx < 65536) {                        // WB1e: (k,e'), x part
    int k = idx >> 8, e = idx & 255;
    WB1e[((k >> 3) * 256 + e) * 8 + (k & 7)] = f2bf(TS * W1[e * 768 + 512 + k]);
    return;
  }
  idx -= 65536;
  if (idx < 256) { b1s[idx] = TS * b1[idx]; return; }
  idx -= 256;
  if (idx < 2048) {                         // Wihs (j,o)
    int j = idx >> 1;
    float sc = ((j >> 8) == 2) ? TS : -LOG2E;
    Wihs[idx] = sc * Wih_in[idx];
    return;
  }
  idx -= 2048;
  if (idx < 1024) {
    int j = idx;
    float sc = ((j >> 8) == 2) ? TS : -LOG2E;
    gbias[j] = sc * (bih[j] + bhh[j]);
    return;
  }
  idx -= 1024;
  if (idx < 4096) {                         // yh2 (b,o)
    int bq = idx >> 1, o = idx & 1;
    float a = bfc[o];
    for (int t = 0; t < 64; ++t) a = fmaf(yhist[bq * 64 + t], Wfc[o * 320 + 256 + t], a);
    yh2[idx] = a;
    return;
  }
}

// ---------------------------------------------------------------------------
// Precompute kernel (unchanged, correctness-proven).
// ---------------------------------------------------------------------------
__global__ __launch_bounds__(256, 4) void kpre(
    const float* __restrict__ x, const unsigned short* __restrict__ WB1e,
    const float* __restrict__ Wfc,
    unsigned short* __restrict__ P, float* __restrict__ ey)
{
  __shared__ __align__(16) unsigned short xs[16384];
  const int bq = blockIdx.x;
  const int tid = threadIdx.x;
  const int w = tid >> 6, lane = tid & 63;
  const float* __restrict__ xb = x + (size_t)bq * 16384;

  #pragma unroll 4
  for (int it = 0; it < 16; ++it) {
    int idx = it * 256 + tid;
    float4 v = *(const float4*)(xb + (size_t)idx * 4);
    int t = idx >> 6, e0 = (idx & 63) * 4;
    unsigned long long pk = (unsigned long long)f2bf(v.x)
        | ((unsigned long long)f2bf(v.y) << 16)
        | ((unsigned long long)f2bf(v.z) << 32)
        | ((unsigned long long)f2bf(v.w) << 48);
    int ba = (t * 512 + e0 * 2) ^ ((t & 7) << 4);
    *(unsigned long long*)((char*)xs + ba) = pk;
  }
  __syncthreads();

  const int mt = w;
  const int fgrp = lane >> 4, fcol = lane & 15;
  const int trow = mt * 16 + fcol;
  s16x8 af[8];
  #pragma unroll
  for (int kb = 0; kb < 8; ++kb) {
    int e = kb * 32 + fgrp * 8;
    int ba = (trow * 512 + e * 2) ^ ((trow & 7) << 4);
    af[kb] = *(const s16x8*)((char*)xs + ba);
  }
  __syncthreads();

  unsigned short* __restrict__ Pst = xs;
  #pragma unroll
  for (int nt = 0; nt < 16; ++nt) {
    s16x8 bfr[8];
    #pragma unroll
    for (int kb = 0; kb < 8; ++kb)
      bfr[kb] = *(const s16x8*)&WB1e[(size_t)((kb * 4 + fgrp) * 256 + nt * 16 + fcol) * 8];
    f32x4 acc = {0.f, 0.f, 0.f, 0.f};
    #pragma unroll
    for (int kb = 0; kb < 8; ++kb)
      acc = __builtin_amdgcn_mfma_f32_16x16x32_bf16(af[kb], bfr[kb], acc, 0, 0, 0);
    const int ep = nt * 16 + fcol;
    #pragma unroll
    for (int r = 0; r < 4; ++r)
      Pst[(mt * 16 + fgrp * 4 + r) * 256 + ep] = f2bf(acc[r]);
  }
  __syncthreads();

  unsigned int* __restrict__ Pd = (unsigned int*)(P + (size_t)bq * 16384);
  #pragma unroll 4
  for (int d = tid; d < 8192; d += 256) {
    int f = d * 2;
    int ec = f >> 9, t = (f >> 3) & 63, i0 = f & 7;
    unsigned int lo = Pst[t * 256 + ec * 8 + i0];
    unsigned int hi = Pst[t * 256 + ec * 8 + i0 + 1];
    Pd[d] = lo | (hi << 16);
  }

  if (tid < 128) {
    int t = tid >> 1, o = tid & 1;
    float a = 0.f;
    const float* __restrict__ xr = xb + t * 256;
    const float* __restrict__ wr = Wfc + o * 320;
    #pragma unroll 4
    for (int e = 0; e < 256; ++e) a = fmaf(xr[e], wr[e], a);
    ey[((size_t)bq * 64 + t) * 2 + o] = a;
  }
}

// ---------------------------------------------------------------------------
// Recurrence v6: 1024 threads / 16 waves, 2 waves per batch row.
// P fully register-resident: 16 chunks = 64 VGPR per wave (its row-half).
// Peak VGPR demand ~115 < 128 budget -> structurally spill-free.
// LDS ~52 KB. 4 waves/SIMD. 4 barriers/step.
// ---------------------------------------------------------------------------
#define SIG(X) __builtin_amdgcn_rcpf(1.f + __builtin_amdgcn_exp2f(X))

#define SCCHUNK(PV, U) do { \
  const float4 qa_ = *(const float4*)(qrowh + (U) * 8); \
  const float4 qc_ = *(const float4*)(qrowh + (U) * 8 + 4); \
  const float4 wa_ = *(const float4*)(w2h + (U) * 8); \
  const float4 wc_ = *(const float4*)(w2h + (U) * 8 + 4); \
  a0 = fmaf(wa_.x, SIG(bf2f((unsigned short)(PV)[0]) + qa_.x), a0); \
  a1 = fmaf(wa_.y, SIG(bf2f((unsigned short)(PV)[1]) + qa_.y), a1); \
  a2 = fmaf(wa_.z, SIG(bf2f((unsigned short)(PV)[2]) + qa_.z), a2); \
  a3 = fmaf(wa_.w, SIG(bf2f((unsigned short)(PV)[3]) + qa_.w), a3); \
  a0 = fmaf(wc_.x, SIG(bf2f((unsigned short)(PV)[4]) + qc_.x), a0); \
  a1 = fmaf(wc_.y, SIG(bf2f((unsigned short)(PV)[5]) + qc_.y), a1); \
  a2 = fmaf(wc_.z, SIG(bf2f((unsigned short)(PV)[6]) + qc_.z), a2); \
  a3 = fmaf(wc_.w, SIG(bf2f((unsigned short)(PV)[7]) + qc_.w), a3); \
} while (0)

#define AHF(KB) (*(const s16x8*)&hcA[(((KB) * 4 + fgrp) * 8 + frow) * 8])

// 4 gate-units per wave: unit GG covers j = GG*256 + wv*16 + 0..15, full K=256 (h).
#define GUNIT4(GG) do { \
  const int jg_ = (GG) * 256 + wv * 16 + fcol; \
  const size_t jb_ = (size_t)jg_ * 8; \
  const s16x8 wb0_ = *(const s16x8*)&WBhh[jb_ + (size_t)(0 * 4 + fgrp) * 8192]; \
  const s16x8 wb1_ = *(const s16x8*)&WBhh[jb_ + (size_t)(1 * 4 + fgrp) * 8192]; \
  const s16x8 wb2_ = *(const s16x8*)&WBhh[jb_ + (size_t)(2 * 4 + fgrp) * 8192]; \
  const s16x8 wb3_ = *(const s16x8*)&WBhh[jb_ + (size_t)(3 * 4 + fgrp) * 8192]; \
  const s16x8 wb4_ = *(const s16x8*)&WBhh[jb_ + (size_t)(4 * 4 + fgrp) * 8192]; \
  const s16x8 wb5_ = *(const s16x8*)&WBhh[jb_ + (size_t)(5 * 4 + fgrp) * 8192]; \
  const s16x8 wb6_ = *(const s16x8*)&WBhh[jb_ + (size_t)(6 * 4 + fgrp) * 8192]; \
  const s16x8 wb7_ = *(const s16x8*)&WBhh[jb_ + (size_t)(7 * 4 + fgrp) * 8192]; \
  const float gbj_ = gbS[jg_]; \
  GA##GG = (f32x4){gbj_, gbj_, gbj_, gbj_}; \
  GA##GG = __builtin_amdgcn_mfma_f32_16x16x32_bf16(AHF(0), wb0_, GA##GG, 0, 0, 0); \
  GA##GG = __builtin_amdgcn_mfma_f32_16x16x32_bf16(AHF(1), wb1_, GA##GG, 0, 0, 0); \
  GA##GG = __builtin_amdgcn_mfma_f32_16x16x32_bf16(AHF(2), wb2_, GA##GG, 0, 0, 0); \
  GA##GG = __builtin_amdgcn_mfma_f32_16x16x32_bf16(AHF(3), wb3_, GA##GG, 0, 0, 0); \
  GA##GG = __builtin_amdgcn_mfma_f32_16x16x32_bf16(AHF(4), wb4_, GA##GG, 0, 0, 0); \
  GA##GG = __builtin_amdgcn_mfma_f32_16x16x32_bf16(AHF(5), wb5_, GA##GG, 0, 0, 0); \
  GA##GG = __builtin_amdgcn_mfma_f32_16x16x32_bf16(AHF(6), wb6_, GA##GG, 0, 0, 0); \
  GA##GG = __builtin_amdgcn_mfma_f32_16x16x32_bf16(AHF(7), wb7_, GA##GG, 0, 0, 0); \
} while (0)

#define PWR(R, CV) do { \
  const int row_ = drow0 + (R); \
  const float y0_ = yt[row_][0], y1_ = yt[row_][1]; \
  const float gi_ = GA0[R] + fmaf(wI0, y0_, wI1 * y1_); \
  const float gf_ = GA1[R] + fmaf(wF0, y0_, wF1 * y1_); \
  const float gg_ = GA2[R] + fmaf(wG0, y0_, wG1 * y1_); \
  const float go_ = GA3[R] + fmaf(wO0, y0_, wO1 * y1_); \
  const float si_ = SIG(gi_); \
  const float sf_ = SIG(gf_); \
  const float tg_ = 1.f - 2.f * SIG(gg_); \
  const float so_ = SIG(go_); \
  const float cn_ = sf_ * (CV) + si_ * tg_; \
  (CV) = cn_; \
  const float th_ = 1.f - 2.f * SIG(2.f * LOG2E * cn_); \
  const float hn_ = so_ * th_; \
  hcA[((jj >> 3) * 8 + row_) * 8 + (jj & 7)] = f2bf(hn_); \
  hcA[((32 + (jj >> 3)) * 8 + row_) * 8 + (jj & 7)] = f2bf(cn_); \
  if (s == 63) hF[row_][jj] = hn_; \
} while (0)

#define PLOADR(U) const s16x8 p##U = *(const s16x8*)(Pb + (U) * 512 + lane * 8);

__global__
__attribute__((amdgpu_flat_work_group_size(1024, 1024), amdgpu_waves_per_eu(4, 4)))
void krecur(
    const float* __restrict__ x, const float* __restrict__ w2g,
    const unsigned short* __restrict__ WB1, const unsigned short* __restrict__ WBhh,
    const float* __restrict__ Wihs, const float* __restrict__ gbias,
    const float* __restrict__ b1s, const float* __restrict__ yh2,
    const float* __restrict__ ey, const unsigned short* __restrict__ P,
    const float* __restrict__ Wfin, const float* __restrict__ bfin,
    float* __restrict__ out)
{
  __shared__ __align__(16) unsigned short hcA[4096];   // 8 KB [k>>3][row][k&7]
  __shared__ __align__(16) float qf[8][256];           // 8 KB
  __shared__ __align__(16) float w2f[256];             // 1 KB
  __shared__ __align__(16) float ps[8][2][64];         // 4 KB score partials
  __shared__ __align__(16) float scAl[8][64];          // 2 KB
  __shared__ float yt[8][2];
  __shared__ __align__(16) float wi0S[1024];           // 4 KB
  __shared__ __align__(16) float wi1S[1024];           // 4 KB
  __shared__ __align__(16) float gbS[1024];            // 4 KB
  __shared__ __align__(16) float hF[8][256];           // 8 KB
  __shared__ __align__(16) float ctxS[8][256];         // 8 KB   (~51 KB total)

  const int tid = threadIdx.x;
  const int wv = tid >> 6, lane = tid & 63;
  const int row = wv >> 1, half = wv & 1;
  const int gbase = blockIdx.x * 8;
  const int gb = gbase + row;

  for (int i = tid; i < 4096; i += 1024) hcA[i] = 0;
  if (tid < 256) w2f[tid] = w2g[tid];
  wi0S[tid] = Wihs[2 * tid];
  wi1S[tid] = Wihs[2 * tid + 1];
  gbS[tid]  = gbias[tid];

  const int frow = lane & 7;
  const int fgrp = lane >> 4;
  const int fcol = lane & 15;
  const int drow0 = fgrp * 4;

  // P: this wave's (row, half) -> 16 named s16x8 chunks (64 VGPR)
  const unsigned short* __restrict__ Pb = P + (size_t)gb * 16384 + (size_t)half * 8192;
  PLOADR(0)  PLOADR(1)  PLOADR(2)  PLOADR(3)
  PLOADR(4)  PLOADR(5)  PLOADR(6)  PLOADR(7)
  PLOADR(8)  PLOADR(9)  PLOADR(10) PLOADR(11)
  PLOADR(12) PLOADR(13) PLOADR(14) PLOADR(15)

  const float2 eyv = *(const float2*)(ey + ((size_t)gb * 64 + lane) * 2);
  const float yh0 = yh2[gb * 2], yh1 = yh2[gb * 2 + 1];
  const float b1r = b1s[wv * 16 + fcol];

  float c0 = 0.f, c1 = 0.f, c2 = 0.f, c3 = 0.f;

  __syncthreads();

  for (int s = 0; s < 64; ++s) {
    // ---- phase1: q N-tile (eb = wv*16), K=512 over h|c ----
    {
      f32x4 acc = {0.f, 0.f, 0.f, 0.f};
      #pragma unroll
      for (int kb = 0; kb < 16; ++kb) {
        const s16x8 bfr = *(const s16x8*)&WB1[(size_t)((kb * 4 + fgrp) * 256 + wv * 16 + fcol) * 8];
        acc = __builtin_amdgcn_mfma_f32_16x16x32_bf16(AHF(kb), bfr, acc, 0, 0, 0);
      }
      if (lane < 32) {
        #pragma unroll
        for (int r = 0; r < 4; ++r) qf[drow0 + r][wv * 16 + fcol] = acc[r] + b1r;
      }
    }
    __syncthreads();                                   // B1: qf ready

    // ---- phase2a: partial scores over this wave's 16 chunks ----
    {
      const float* __restrict__ qrowh = &qf[row][0] + half * 128;
      const float* __restrict__ w2h = w2f + half * 128;
      float a0 = 0.f, a1 = 0.f, a2 = 0.f, a3 = 0.f;
      SCCHUNK(p0, 0);   SCCHUNK(p1, 1);   SCCHUNK(p2, 2);   SCCHUNK(p3, 3);
      SCCHUNK(p4, 4);   SCCHUNK(p5, 5);   SCCHUNK(p6, 6);   SCCHUNK(p7, 7);
      SCCHUNK(p8, 8);   SCCHUNK(p9, 9);   SCCHUNK(p10, 10); SCCHUNK(p11, 11);
      SCCHUNK(p12, 12); SCCHUNK(p13, 13); SCCHUNK(p14, 14); SCCHUNK(p15, 15);
      ps[row][half][lane] = (a0 + a1) + (a2 + a3);
    }
    __syncthreads();                                   // B2: partials ready

    // ---- phase2b: gates MFMA (WBhh stream, no yt dep) + softmax ----
    f32x4 GA0, GA1, GA2, GA3;
    GUNIT4(0); GUNIT4(1); GUNIT4(2); GUNIT4(3);
    {
      float sc = -2.f * (ps[row][0][lane] + ps[row][1][lane]);
      float mx = wredmax(sc);
      float e_t = __builtin_amdgcn_exp2f((sc - mx) * LOG2E);
      float sm = wredsum(e_t);
      float alpha = e_t * __builtin_amdgcn_rcpf(sm);
      if (s == 63 && half == 0) scAl[row][lane] = alpha;
      float y0 = wredsum(alpha * eyv.x);
      float y1 = wredsum(alpha * eyv.y);
      if (half == 0 && lane == 0) { yt[row][0] = y0 + yh0; yt[row][1] = y1 + yh1; }
    }
    __syncthreads();                                   // B3: yt ready

    // ---- phase3: pointwise, state update (16 cols per wave) ----
    if (lane < 32) {
      const int jj = wv * 16 + fcol;
      const float wI0 = wi0S[jj],       wI1 = wi1S[jj];
      const float wF0 = wi0S[256 + jj], wF1 = wi1S[256 + jj];
      const float wG0 = wi0S[512 + jj], wG1 = wi1S[512 + jj];
      const float wO0 = wi0S[768 + jj], wO1 = wi1S[768 + jj];
      PWR(0, c0); PWR(1, c1); PWR(2, c2); PWR(3, c3);
    }
    __syncthreads();                                   // B4: hcA ready

    if (s == 63) {   // ctx[row][e] = sum_t alpha_t * x[gb,t,e]; wave does 2 e-blocks
      #pragma unroll
      for (int pp = 0; pp < 2; ++pp) {
        const int e = (half * 2 + pp) * 64 + lane;
        float a = 0.f;
        const float* __restrict__ xr = x + (size_t)gb * 16384 + e;
        #pragma unroll 8
        for (int t = 0; t < 64; ++t) a = fmaf(scAl[row][t], xr[t * 256], a);
        ctxS[row][e] = a;
      }
      __syncthreads();
    }
  }

  // ---- final: out = [h, ctx] @ W_final.T + b_final (half0 waves only) ----
  if (half == 0) {
    float o0 = 0.f, o1 = 0.f;
    #pragma unroll
    for (int kk = 0; kk < 8; ++kk) {
      const int k = kk * 64 + lane;
      const float v = (k < 256) ? hF[row][k] : ctxS[row][k - 256];
      o0 = fmaf(v, Wfin[k], o0);
      o1 = fmaf(v, Wfin[512 + k], o1);
    }
    o0 = wredsum(o0);
    o1 = wredsum(o1);
    if (lane == 0) {
      out[gb * 2 + 0] = o0 + bfin[0];
      out[gb * 2 + 1] = o1 + bfin[1];
    }
  }
}

// ---------------------------------------------------------------------------
extern "C" void kernel_launch(void* const* d_in, const int* in_sizes, int n_in,
                              void* d_out, int out_size, void* d_ws, size_t ws_size,
                              hipStream_t stream) {
  const float* x    = (const float*)d_in[0];
  const float* yh   = (const float*)d_in[1];
  const float* W1   = (const float*)d_in[2];
  const float* b1   = (const float*)d_in[3];
  const float* w2   = (const float*)d_in[4];
  // d_in[5] = b2: softmax-invariant -> unused
  const float* Wih  = (const float*)d_in[6];
  const float* bih  = (const float*)d_in[7];
  const float* Whh  = (const float*)d_in[8];
  const float* bhh  = (const float*)d_in[9];
  const float* Wfc  = (const float*)d_in[10];
  const float* bfc  = (const float*)d_in[11];
  const float* Wfin = (const float*)d_in[12];
  const float* bfin = (const float*)d_in[13];

  char* ws = (char*)d_ws;
  unsigned short* P    = (unsigned short*)(ws + 0);          // 67,108,864 B
  unsigned short* WB1  = (unsigned short*)(ws + 67108864);   //    262,144 B
  unsigned short* WBhh = (unsigned short*)(ws + 67371008);   //    524,288 B
  unsigned short* WB1e = (unsigned short*)(ws + 67895296);   //    131,072 B
  float* b1s   = (float*)(ws + 68026368);                    //      1,024 B
  float* Wihs  = (float*)(ws + 68027392);                    //      8,192 B
  float* gbias = (float*)(ws + 68035584);                    //      4,096 B
  float* yh2   = (float*)(ws + 68039680);                    //     16,384 B
  float* ey    = (float*)(ws + 68056064);                    //  1,048,576 B -> 69,104,640 total

  ktrans<<<1821, 256, 0, stream>>>(W1, b1, Wih, bih, Whh, bhh, Wfc, bfc, yh,
                                   WB1, WBhh, WB1e, b1s, Wihs, gbias, yh2);
  kpre<<<2048, 256, 0, stream>>>(x, WB1e, Wfc, P, ey);
  krecur<<<256, 1024, 0, stream>>>(x, w2, WB1, WBhh, Wihs, gbias, b1s, yh2, ey, P,
                                   Wfin, bfin, (float*)d_out);
}

// Round 7
// 3909.536 us; speedup vs baseline: 1.1691x; 1.1691x over previous
//
#include <hip/hip_runtime.h>
#include <hip/hip_bf16.h>
#include <cstdint>
#include <cstddef>

#define LOG2E 1.44269504088896340736f

using f32x4 = __attribute__((ext_vector_type(4))) float;
using s16x8 = __attribute__((ext_vector_type(8))) short;

static __device__ __forceinline__ float bf2f(unsigned short u) {
  union { unsigned int i; float f; } v; v.i = ((unsigned int)u) << 16; return v.f;
}
static __device__ __forceinline__ unsigned short f2bf(float f) {
  union { float f; unsigned int i; } v; v.f = f;
  unsigned int r = v.i + 0x7fffu + ((v.i >> 16) & 1u);
  return (unsigned short)(r >> 16);
}
static __device__ __forceinline__ float wredmax(float v) {
  #pragma unroll
  for (int m = 32; m > 0; m >>= 1) v = fmaxf(v, __shfl_xor(v, m, 64));
  return v;
}
static __device__ __forceinline__ float wredsum(float v) {
  #pragma unroll
  for (int m = 32; m > 0; m >>= 1) v += __shfl_xor(v, m, 64);
  return v;
}

// ---------------------------------------------------------------------------
// Transform kernel (unchanged).
// ---------------------------------------------------------------------------
__global__ void ktrans(const float* __restrict__ W1, const float* __restrict__ b1,
                       const float* __restrict__ Wih_in, const float* __restrict__ bih,
                       const float* __restrict__ Whh, const float* __restrict__ bhh,
                       const float* __restrict__ Wfc, const float* __restrict__ bfc,
                       const float* __restrict__ yhist,
                       unsigned short* __restrict__ WB1, unsigned short* __restrict__ WBhh,
                       unsigned short* __restrict__ WB1e, float* __restrict__ b1s,
                       float* __restrict__ Wihs, float* __restrict__ gbias,
                       float* __restrict__ yh2)
{
  int idx = blockIdx.x * 256 + threadIdx.x;
  const float TS = 2.f * LOG2E;
  if (idx < 131072) {                       // WB1: (k,e')
    int k = idx >> 8, e = idx & 255;
    WB1[((k >> 3) * 256 + e) * 8 + (k & 7)] = f2bf(TS * W1[e * 768 + k]);
    return;
  }
  idx -= 131072;
  if (idx < 262144) {                       // WBhh: (k,j)
    int k = idx >> 10, j = idx & 1023;
    float sc = ((j >> 8) == 2) ? TS : -LOG2E;
    WBhh[((k >> 3) * 1024 + j) * 8 + (k & 7)] = f2bf(sc * Whh[j * 256 + k]);
    return;
  }
  idx -= 262144;
  if (idx < 65536) {                        // WB1e: (k,e'), x part
    int k = idx >> 8, e = idx & 255;
    WB1e[((k >> 3) * 256 + e) * 8 + (k & 7)] = f2bf(TS * W1[e * 768 + 512 + k]);
    return;
  }
  idx -= 65536;
  if (idx < 256) { b1s[idx] = TS * b1[idx]; return; }
  idx -= 256;
  if (idx < 2048) {                         // Wihs (j,o)
    int j = idx >> 1;
    float sc = ((j >> 8) == 2) ? TS : -LOG2E;
    Wihs[idx] = sc * Wih_in[idx];
    return;
  }
  idx -= 2048;
  if (idx < 1024) {
    int j = idx;
    float sc = ((j >> 8) == 2) ? TS : -LOG2E;
    gbias[j] = sc * (bih[j] + bhh[j]);
    return;
  }
  idx -= 1024;
  if (idx < 4096) {                         // yh2 (b,o)
    int bq = idx >> 1, o = idx & 1;
    float a = bfc[o];
    for (int t = 0; t < 64; ++t) a = fmaf(yhist[bq * 64 + t], Wfc[o * 320 + 256 + t], a);
    yh2[idx] = a;
    return;
  }
}

// ---------------------------------------------------------------------------
// Precompute kernel (unchanged, correctness-proven).
// ---------------------------------------------------------------------------
__global__ __launch_bounds__(256, 4) void kpre(
    const float* __restrict__ x, const unsigned short* __restrict__ WB1e,
    const float* __restrict__ Wfc,
    unsigned short* __restrict__ P, float* __restrict__ ey)
{
  __shared__ __align__(16) unsigned short xs[16384];
  const int bq = blockIdx.x;
  const int tid = threadIdx.x;
  const int w = tid >> 6, lane = tid & 63;
  const float* __restrict__ xb = x + (size_t)bq * 16384;

  #pragma unroll 4
  for (int it = 0; it < 16; ++it) {
    int idx = it * 256 + tid;
    float4 v = *(const float4*)(xb + (size_t)idx * 4);
    int t = idx >> 6, e0 = (idx & 63) * 4;
    unsigned long long pk = (unsigned long long)f2bf(v.x)
        | ((unsigned long long)f2bf(v.y) << 16)
        | ((unsigned long long)f2bf(v.z) << 32)
        | ((unsigned long long)f2bf(v.w) << 48);
    int ba = (t * 512 + e0 * 2) ^ ((t & 7) << 4);
    *(unsigned long long*)((char*)xs + ba) = pk;
  }
  __syncthreads();

  const int mt = w;
  const int fgrp = lane >> 4, fcol = lane & 15;
  const int trow = mt * 16 + fcol;
  s16x8 af[8];
  #pragma unroll
  for (int kb = 0; kb < 8; ++kb) {
    int e = kb * 32 + fgrp * 8;
    int ba = (trow * 512 + e * 2) ^ ((trow & 7) << 4);
    af[kb] = *(const s16x8*)((char*)xs + ba);
  }
  __syncthreads();

  unsigned short* __restrict__ Pst = xs;
  #pragma unroll
  for (int nt = 0; nt < 16; ++nt) {
    s16x8 bfr[8];
    #pragma unroll
    for (int kb = 0; kb < 8; ++kb)
      bfr[kb] = *(const s16x8*)&WB1e[(size_t)((kb * 4 + fgrp) * 256 + nt * 16 + fcol) * 8];
    f32x4 acc = {0.f, 0.f, 0.f, 0.f};
    #pragma unroll
    for (int kb = 0; kb < 8; ++kb)
      acc = __builtin_amdgcn_mfma_f32_16x16x32_bf16(af[kb], bfr[kb], acc, 0, 0, 0);
    const int ep = nt * 16 + fcol;
    #pragma unroll
    for (int r = 0; r < 4; ++r)
      Pst[(mt * 16 + fgrp * 4 + r) * 256 + ep] = f2bf(acc[r]);
  }
  __syncthreads();

  unsigned int* __restrict__ Pd = (unsigned int*)(P + (size_t)bq * 16384);
  #pragma unroll 4
  for (int d = tid; d < 8192; d += 256) {
    int f = d * 2;
    int ec = f >> 9, t = (f >> 3) & 63, i0 = f & 7;
    unsigned int lo = Pst[t * 256 + ec * 8 + i0];
    unsigned int hi = Pst[t * 256 + ec * 8 + i0 + 1];
    Pd[d] = lo | (hi << 16);
  }

  if (tid < 128) {
    int t = tid >> 1, o = tid & 1;
    float a = 0.f;
    const float* __restrict__ xr = xb + t * 256;
    const float* __restrict__ wr = Wfc + o * 320;
    #pragma unroll 4
    for (int e = 0; e < 256; ++e) a = fmaf(xr[e], wr[e], a);
    ey[((size_t)bq * 64 + t) * 2 + o] = a;
  }
}

// ---------------------------------------------------------------------------
// Recurrence v7: demand-fits-budget design. 1024 thr / 16 waves, wave=(row,half).
// P: 8 chunks in regs (32 VGPR) + 8 chunks in LDS (128 KB total).
// Matmuls shaped for low register pressure: per kb {1 A-frag, <=4 B-frags, MFMAs}.
// LDS 155 KB -> 1 WG/CU -> heuristic budget 128 VGPR; demand ~115.
// ---------------------------------------------------------------------------
#define SIG(X) __builtin_amdgcn_rcpf(1.f + __builtin_amdgcn_exp2f(X))

#define SCCHUNK(PV, U) do { \
  const float4 qa_ = *(const float4*)(qrowh + (U) * 8); \
  const float4 qc_ = *(const float4*)(qrowh + (U) * 8 + 4); \
  const float4 wa_ = *(const float4*)(w2h + (U) * 8); \
  const float4 wc_ = *(const float4*)(w2h + (U) * 8 + 4); \
  a0 = fmaf(wa_.x, SIG(bf2f((unsigned short)(PV)[0]) + qa_.x), a0); \
  a1 = fmaf(wa_.y, SIG(bf2f((unsigned short)(PV)[1]) + qa_.y), a1); \
  a2 = fmaf(wa_.z, SIG(bf2f((unsigned short)(PV)[2]) + qa_.z), a2); \
  a3 = fmaf(wa_.w, SIG(bf2f((unsigned short)(PV)[3]) + qa_.w), a3); \
  a0 = fmaf(wc_.x, SIG(bf2f((unsigned short)(PV)[4]) + qc_.x), a0); \
  a1 = fmaf(wc_.y, SIG(bf2f((unsigned short)(PV)[5]) + qc_.y), a1); \
  a2 = fmaf(wc_.z, SIG(bf2f((unsigned short)(PV)[6]) + qc_.z), a2); \
  a3 = fmaf(wc_.w, SIG(bf2f((unsigned short)(PV)[7]) + qc_.w), a3); \
} while (0)

#define SCL(U) do { \
  const s16x8 pvL_ = *(const s16x8*)&Pl[row][half][(U) - 8][lane][0]; \
  SCCHUNK(pvL_, U); \
} while (0)

#define AHF(KB) (*(const s16x8*)&hcA[(((KB) * 4 + fgrp) * 8 + frow) * 8])

#define PWR(R, CV) do { \
  const int row_ = drow0 + (R); \
  const float y0_ = yt[row_][0], y1_ = yt[row_][1]; \
  const float gi_ = GA0[R] + fmaf(wI0, y0_, wI1 * y1_); \
  const float gf_ = GA1[R] + fmaf(wF0, y0_, wF1 * y1_); \
  const float gg_ = GA2[R] + fmaf(wG0, y0_, wG1 * y1_); \
  const float go_ = GA3[R] + fmaf(wO0, y0_, wO1 * y1_); \
  const float si_ = SIG(gi_); \
  const float sf_ = SIG(gf_); \
  const float tg_ = 1.f - 2.f * SIG(gg_); \
  const float so_ = SIG(go_); \
  const float cn_ = sf_ * (CV) + si_ * tg_; \
  (CV) = cn_; \
  const float th_ = 1.f - 2.f * SIG(2.f * LOG2E * cn_); \
  const float hn_ = so_ * th_; \
  hcA[((jj0 >> 3) * 8 + row_) * 8 + (jj0 & 7)] = f2bf(hn_); \
  hcA[((32 + (jj0 >> 3)) * 8 + row_) * 8 + (jj0 & 7)] = f2bf(cn_); \
  if (s == 63) hF[row_ * 256 + jj0] = hn_; \
} while (0)

#define PLOADR(U) const s16x8 p##U = *(const s16x8*)(Pb + (size_t)(U) * 512 + lane * 8);

__global__ __launch_bounds__(1024) void krecur(
    const float* __restrict__ x, const float* __restrict__ w2g,
    const unsigned short* __restrict__ WB1, const unsigned short* __restrict__ WBhh,
    const float* __restrict__ Wihs, const float* __restrict__ gbias,
    const float* __restrict__ b1s, const float* __restrict__ yh2,
    const float* __restrict__ ey, const unsigned short* __restrict__ P,
    const float* __restrict__ Wfin, const float* __restrict__ bfin,
    float* __restrict__ out)
{
  __shared__ __align__(16) unsigned short Pl[8][2][8][64][8]; // 128 KB; hF/ctx alias @s=63
  __shared__ __align__(16) unsigned short hcA[4096];          // 8 KB [k>>3][row][k&7]
  __shared__ __align__(16) float qf[8][256];                  // 8 KB
  __shared__ __align__(16) float w2f[256];                    // 1 KB
  __shared__ __align__(16) float ps[8][2][64];                // 4 KB score partials
  __shared__ __align__(16) float scAl[8][64];                 // 2 KB
  __shared__ float yt[8][2];                                  // ~155 KB total

  float* const hF   = (float*)&Pl[0][0][0][0][0];   // [8][256] f32, bytes 0..8191
  float* const ctxS = hF + 2048;                    // [8][256] f32, bytes 8192..16383

  const int tid = threadIdx.x;
  const int wv = tid >> 6, lane = tid & 63;
  const int row = wv >> 1, half = wv & 1;
  const int gbase = blockIdx.x * 8;
  const int gb = gbase + row;

  for (int i = tid; i < 4096; i += 1024) hcA[i] = 0;
  if (tid < 256) w2f[tid] = w2g[tid];
  // P LDS chunks: wave (row,half)'s chunks u=8..15 (global ec = half*16+8+u')
  for (int i = tid; i < 8192; i += 1024) {
    int rw = i >> 10, rem = i & 1023;
    int hf = rem >> 9, ch = (rem >> 6) & 7, t = rem & 63;
    *(s16x8*)&Pl[rw][hf][ch][t][0] =
        *(const s16x8*)(P + (size_t)(gbase + rw) * 16384 + (size_t)(hf * 16 + 8 + ch) * 512 + t * 8);
  }

  const int frow = lane & 7;
  const int fgrp = lane >> 4;
  const int fcol = lane & 15;
  const int drow0 = fgrp * 4;

  // P reg chunks u=0..7 (global ec = half*16 + u): 8 named s16x8 = 32 VGPR
  const unsigned short* __restrict__ Pb = P + (size_t)gb * 16384 + (size_t)half * 8192;
  PLOADR(0) PLOADR(1) PLOADR(2) PLOADR(3)
  PLOADR(4) PLOADR(5) PLOADR(6) PLOADR(7)

  const float2 eyv = *(const float2*)(ey + ((size_t)gb * 64 + lane) * 2);
  const float yh0 = yh2[gb * 2], yh1 = yh2[gb * 2 + 1];
  const int jj0 = wv * 16 + fcol;
  const float b1r = b1s[jj0];
  const float wI0 = Wihs[2 * jj0],          wI1 = Wihs[2 * jj0 + 1];
  const float wF0 = Wihs[2 * (256 + jj0)],  wF1 = Wihs[2 * (256 + jj0) + 1];
  const float wG0 = Wihs[2 * (512 + jj0)],  wG1 = Wihs[2 * (512 + jj0) + 1];
  const float wO0 = Wihs[2 * (768 + jj0)],  wO1 = Wihs[2 * (768 + jj0) + 1];
  const float gb_0 = gbias[jj0],       gb_1 = gbias[256 + jj0];
  const float gb_2 = gbias[512 + jj0], gb_3 = gbias[768 + jj0];

  float c0 = 0.f, c1 = 0.f, c2 = 0.f, c3 = 0.f;

  __syncthreads();

  for (int s = 0; s < 64; ++s) {
    // ---- phase1: q col-tile jj0 (K=512 over h|c); per-kb {A,B,mfma} ----
    {
      f32x4 acc = {0.f, 0.f, 0.f, 0.f};
      #pragma unroll
      for (int kb = 0; kb < 16; ++kb) {
        const s16x8 a_ = AHF(kb);
        const s16x8 b_ = *(const s16x8*)&WB1[(size_t)((kb * 4 + fgrp) * 256 + jj0) * 8];
        acc = __builtin_amdgcn_mfma_f32_16x16x32_bf16(a_, b_, acc, 0, 0, 0);
      }
      if (lane < 32) {
        #pragma unroll
        for (int r = 0; r < 4; ++r) qf[drow0 + r][jj0] = acc[r] + b1r;
      }
    }
    __syncthreads();                                   // B1: qf ready

    // ---- phase2a: partial scores over this wave's 16 chunks (8 reg + 8 LDS) ----
    {
      const float* __restrict__ qrowh = &qf[row][0] + half * 128;
      const float* __restrict__ w2h = w2f + half * 128;
      float a0 = 0.f, a1 = 0.f, a2 = 0.f, a3 = 0.f;
      SCCHUNK(p0, 0); SCCHUNK(p1, 1); SCCHUNK(p2, 2); SCCHUNK(p3, 3);
      SCCHUNK(p4, 4); SCCHUNK(p5, 5); SCCHUNK(p6, 6); SCCHUNK(p7, 7);
      SCL(8); SCL(9); SCL(10); SCL(11); SCL(12); SCL(13); SCL(14); SCL(15);
      ps[row][half][lane] = (a0 + a1) + (a2 + a3);
    }
    __syncthreads();                                   // B2: partials ready

    // ---- phase2b: gates MFMA (per-kb: 1 A-frag, 4 B-frags, 4 MFMAs) + softmax ----
    f32x4 GA0 = {gb_0, gb_0, gb_0, gb_0};
    f32x4 GA1 = {gb_1, gb_1, gb_1, gb_1};
    f32x4 GA2 = {gb_2, gb_2, gb_2, gb_2};
    f32x4 GA3 = {gb_3, gb_3, gb_3, gb_3};
    #pragma unroll
    for (int kb = 0; kb < 8; ++kb) {
      const s16x8 a_ = AHF(kb);
      const size_t ko_ = (size_t)(kb * 4 + fgrp) * 8192;
      const s16x8 b0_ = *(const s16x8*)&WBhh[ko_ + (size_t)(jj0) * 8];
      const s16x8 b1_ = *(const s16x8*)&WBhh[ko_ + (size_t)(256 + jj0) * 8];
      const s16x8 b2_ = *(const s16x8*)&WBhh[ko_ + (size_t)(512 + jj0) * 8];
      const s16x8 b3_ = *(const s16x8*)&WBhh[ko_ + (size_t)(768 + jj0) * 8];
      GA0 = __builtin_amdgcn_mfma_f32_16x16x32_bf16(a_, b0_, GA0, 0, 0, 0);
      GA1 = __builtin_amdgcn_mfma_f32_16x16x32_bf16(a_, b1_, GA1, 0, 0, 0);
      GA2 = __builtin_amdgcn_mfma_f32_16x16x32_bf16(a_, b2_, GA2, 0, 0, 0);
      GA3 = __builtin_amdgcn_mfma_f32_16x16x32_bf16(a_, b3_, GA3, 0, 0, 0);
    }
    {
      float sc = -2.f * (ps[row][0][lane] + ps[row][1][lane]);
      float mx = wredmax(sc);
      float e_t = __builtin_amdgcn_exp2f((sc - mx) * LOG2E);
      float sm = wredsum(e_t);
      float alpha = e_t * __builtin_amdgcn_rcpf(sm);
      if (s == 63 && half == 0) scAl[row][lane] = alpha;
      float y0 = wredsum(alpha * eyv.x);
      float y1 = wredsum(alpha * eyv.y);
      if (half == 0 && lane == 0) { yt[row][0] = y0 + yh0; yt[row][1] = y1 + yh1; }
    }
    __syncthreads();                                   // B3: yt ready

    // ---- phase3: pointwise, state update (cols jj0, rows drow0..+3) ----
    if (lane < 32) {
      PWR(0, c0); PWR(1, c1); PWR(2, c2); PWR(3, c3);
    }
    __syncthreads();                                   // B4: hcA ready

    if (s == 63) {   // ctx[row][e] = sum_t alpha_t * x[gb,t,e]; wave does 2 e-blocks
      #pragma unroll
      for (int pp = 0; pp < 2; ++pp) {
        const int e = (half * 2 + pp) * 64 + lane;
        float a = 0.f;
        const float* __restrict__ xr = x + (size_t)gb * 16384 + e;
        #pragma unroll 8
        for (int t = 0; t < 64; ++t) a = fmaf(scAl[row][t], xr[t * 256], a);
        ctxS[row * 256 + e] = a;
      }
      __syncthreads();
    }
  }

  // ---- final: out = [h, ctx] @ W_final.T + b_final (half0 waves only) ----
  if (half == 0) {
    float o0 = 0.f, o1 = 0.f;
    #pragma unroll
    for (int kk = 0; kk < 8; ++kk) {
      const int k = kk * 64 + lane;
      const float v = (k < 256) ? hF[row * 256 + k] : ctxS[row * 256 + (k - 256)];
      o0 = fmaf(v, Wfin[k], o0);
      o1 = fmaf(v, Wfin[512 + k], o1);
    }
    o0 = wredsum(o0);
    o1 = wredsum(o1);
    if (lane == 0) {
      out[gb * 2 + 0] = o0 + bfin[0];
      out[gb * 2 + 1] = o1 + bfin[1];
    }
  }
}

// ---------------------------------------------------------------------------
extern "C" void kernel_launch(void* const* d_in, const int* in_sizes, int n_in,
                              void* d_out, int out_size, void* d_ws, size_t ws_size,
                              hipStream_t stream) {
  const float* x    = (const float*)d_in[0];
  const float* yh   = (const float*)d_in[1];
  const float* W1   = (const float*)d_in[2];
  const float* b1   = (const float*)d_in[3];
  const float* w2   = (const float*)d_in[4];
  // d_in[5] = b2: softmax-invariant -> unused
  const float* Wih  = (const float*)d_in[6];
  const float* bih  = (const float*)d_in[7];
  const float* Whh  = (const float*)d_in[8];
  const float* bhh  = (const float*)d_in[9];
  const float* Wfc  = (const float*)d_in[10];
  const float* bfc  = (const float*)d_in[11];
  const float* Wfin = (const float*)d_in[12];
  const float* bfin = (const float*)d_in[13];

  char* ws = (char*)d_ws;
  unsigned short* P    = (unsigned short*)(ws + 0);          // 67,108,864 B
  unsigned short* WB1  = (unsigned short*)(ws + 67108864);   //    262,144 B
  unsigned short* WBhh = (unsigned short*)(ws + 67371008);   //    524,288 B
  unsigned short* WB1e = (unsigned short*)(ws + 67895296);   //    131,072 B
  float* b1s   = (float*)(ws + 68026368);                    //      1,024 B
  float* Wihs  = (float*)(ws + 68027392);                    //      8,192 B
  float* gbias = (float*)(ws + 68035584);                    //      4,096 B
  float* yh2   = (float*)(ws + 68039680);                    //     16,384 B
  float* ey    = (float*)(ws + 68056064);                    //  1,048,576 B -> 69,104,640 total

  ktrans<<<1821, 256, 0, stream>>>(W1, b1, Wih, bih, Whh, bhh, Wfc, bfc, yh,
                                   WB1, WBhh, WB1e, b1s, Wihs, gbias, yh2);
  kpre<<<2048, 256, 0, stream>>>(x, WB1e, Wfc, P, ey);
  krecur<<<256, 1024, 0, stream>>>(x, w2, WB1, WBhh, Wihs, gbias, b1s, yh2, ey, P,
                                   Wfin, bfin, (float*)d_out);
}